// Round 1
// baseline (1188.277 us; speedup 1.0000x reference)
//
#include <hip/hip_runtime.h>

// Res_EGblk: fused GNN block on MI355X.
// Pipeline: CSR build (hist/scan/scatter) -> node GEMM (h,xw via bf16 MFMA)
// -> edge GEMM lin2 (bf16 MFMA, feat built in LDS from gathers) -> edge BN stats
// -> edge BN+relu+residual+edge-weight -> deg/dinv -> node-parallel CSR gather agg
// -> node BN stats -> BN+relu+residual.
// ef_raw is staged in the out1 region of d_out (E*64 f32). Workspace need ~85 MB.

#define NN 50000
#define NE 800000
#define DN 128
#define DE 64
#define DF 16
#define KP 232      // padded K stride (shorts) for lin2 LDS tiles (208 -> 232)
#define KP1 136     // padded K stride (shorts) for node-gemm LDS tiles (128 -> 136)
#define EPS 1e-5f
#define SCAN_BLOCKS 49   // ceil(50000/1024)

typedef float f32x4 __attribute__((ext_vector_type(4)));
typedef short s16x8 __attribute__((ext_vector_type(8)));
typedef unsigned short u16;

__device__ __forceinline__ float bf2f(u16 u) {
  union { unsigned int i; float f; } v; v.i = ((unsigned int)u) << 16; return v.f;
}
__device__ __forceinline__ u16 f2bf(float f) {
  union { float ff; unsigned int i; } v; v.ff = f;
  unsigned int x = v.i;
  return (u16)((x + 0x7fffu + ((x >> 16) & 1u)) >> 16);   // RNE
}

// ---------------- pre-conversion ----------------
__global__ void kpre_x(const float* __restrict__ x, u16* __restrict__ xbf) {
  int tot = NN * DN / 4;
  for (int i = blockIdx.x * blockDim.x + threadIdx.x; i < tot; i += gridDim.x * blockDim.x) {
    float4 v = ((const float4*)x)[i];
    ushort4 o;
    o.x = f2bf(v.x); o.y = f2bf(v.y); o.z = f2bf(v.z); o.w = f2bf(v.w);
    ((ushort4*)xbf)[i] = o;
  }
}

__global__ void kpre_w(const float* __restrict__ lin1w, const float* __restrict__ gcnw,
                       const float* __restrict__ lin2w,
                       u16* __restrict__ WcatT, u16* __restrict__ l2wT) {
  int t = threadIdx.x;  // 256 threads
  // WcatT[256][128]: col-major-transposed [W1 | Wg], bf16
  for (int k = 0; k < DN; ++k) {
    float v = (t < DN) ? lin1w[k * DN + t] : gcnw[k * DN + (t - DN)];
    WcatT[t * DN + k] = f2bf(v);
  }
  // l2wT[64][232]: lin2_w transposed, K padded with zeros
  if (t < DE) {
    for (int k = 0; k < KP; ++k) {
      float v = (k < (DN + DE + DF)) ? lin2w[k * DE + t] : 0.f;
      l2wT[t * KP + k] = f2bf(v);
    }
  }
}

// ---------------- CSR build ----------------
__global__ void khist(const int* __restrict__ ei, int* __restrict__ cnt) {
  for (int i = blockIdx.x * blockDim.x + threadIdx.x; i < NE; i += gridDim.x * blockDim.x)
    atomicAdd(&cnt[ei[NE + i]], 1);
}

__global__ void kscan1(const int* __restrict__ cnt, int* __restrict__ rowst, int* __restrict__ blks) {
  __shared__ int ls[256];
  int b = blockIdx.x, t = threadIdx.x;
  int base = b * 1024 + t * 4;
  int c0 = base     < NN ? cnt[base]     : 0;
  int c1 = base + 1 < NN ? cnt[base + 1] : 0;
  int c2 = base + 2 < NN ? cnt[base + 2] : 0;
  int c3 = base + 3 < NN ? cnt[base + 3] : 0;
  int s = c0 + c1 + c2 + c3;
  ls[t] = s; __syncthreads();
  for (int off = 1; off < 256; off <<= 1) {
    int v = (t >= off) ? ls[t - off] : 0;
    __syncthreads();
    ls[t] += v;
    __syncthreads();
  }
  int excl = ls[t] - s;
  if (t == 255) blks[b] = ls[255];
  if (base     < NN) rowst[base]     = excl;
  if (base + 1 < NN) rowst[base + 1] = excl + c0;
  if (base + 2 < NN) rowst[base + 2] = excl + c0 + c1;
  if (base + 3 < NN) rowst[base + 3] = excl + c0 + c1 + c2;
}

__global__ void kscan2(int* __restrict__ blks) {
  if (threadIdx.x == 0) {
    int run = 0;
    for (int i = 0; i < SCAN_BLOCKS; ++i) { int v = blks[i]; blks[i] = run; run += v; }
  }
}

__global__ void kscan3(const int* __restrict__ blks, int* __restrict__ rowst, int* __restrict__ cur) {
  int b = blockIdx.x, t = threadIdx.x;
  int add = blks[b];
  int base = b * 1024 + t * 4;
#pragma unroll
  for (int j = 0; j < 4; ++j) {
    int i = base + j;
    if (i < NN) { int v = rowst[i] + add; rowst[i] = v; cur[i] = v; }
  }
  if (b == 0 && t == 0) rowst[NN] = NE;
}

__global__ void kscat(const int* __restrict__ ei, int* __restrict__ cur, int* __restrict__ csr) {
  for (int i = blockIdx.x * blockDim.x + threadIdx.x; i < NE; i += gridDim.x * blockDim.x) {
    int n = ei[NE + i];
    int p = atomicAdd(&cur[n], 1);
    csr[p] = i;
  }
}

// ---------------- node GEMM: h = x@W1+b1 (bf16 out), xw = x@Wg (f32 out) ----------------
__global__ void __launch_bounds__(256) k_nodegemm(
    const u16* __restrict__ xbf, const u16* __restrict__ WcatT,
    const float* __restrict__ lin1b,
    u16* __restrict__ hbf, float* __restrict__ xw)
{
  __shared__ __align__(16) u16 As[64 * KP1];
  __shared__ __align__(16) u16 Bs[64 * KP1];
  int tid = threadIdx.x;
  int tile = blockIdx.x >> 2, ct = blockIdx.x & 3;
  int n0 = tile * 64, c0 = ct * 64;
  int r = tid >> 2, q = tid & 3;
  {
    int n = n0 + r;
    s16x8* dst = (s16x8*)(As + r * KP1 + q * 32);
    if (n < NN) {
      const s16x8* src = (const s16x8*)(xbf + n * DN + q * 32);
      dst[0] = src[0]; dst[1] = src[1]; dst[2] = src[2]; dst[3] = src[3];
    } else {
      s16x8 z = {0,0,0,0,0,0,0,0};
      dst[0] = z; dst[1] = z; dst[2] = z; dst[3] = z;
    }
    const s16x8* bsrc = (const s16x8*)(WcatT + (c0 + r) * DN + q * 32);
    s16x8* bdst = (s16x8*)(Bs + r * KP1 + q * 32);
    bdst[0] = bsrc[0]; bdst[1] = bsrc[1]; bdst[2] = bsrc[2]; bdst[3] = bsrc[3];
  }
  __syncthreads();
  int w = tid >> 6, l = tid & 63, lr = l & 15, lg = l >> 4;
  f32x4 acc[4] = {{0,0,0,0},{0,0,0,0},{0,0,0,0},{0,0,0,0}};
  for (int kt = 0; kt < 4; ++kt) {
    s16x8 av = *(const s16x8*)(As + (w * 16 + lr) * KP1 + kt * 32 + lg * 8);
#pragma unroll
    for (int nt = 0; nt < 4; ++nt) {
      s16x8 bv = *(const s16x8*)(Bs + (nt * 16 + lr) * KP1 + kt * 32 + lg * 8);
      acc[nt] = __builtin_amdgcn_mfma_f32_16x16x32_bf16(av, bv, acc[nt], 0, 0, 0);
    }
  }
#pragma unroll
  for (int nt = 0; nt < 4; ++nt) {
    int gcol = c0 + nt * 16 + lr;
#pragma unroll
    for (int rr = 0; rr < 4; ++rr) {
      int n = n0 + w * 16 + lg * 4 + rr;
      if (n < NN) {
        float v = acc[nt][rr];
        if (gcol < DN) hbf[n * DN + gcol] = f2bf(v + lin1b[gcol]);
        else           xw[n * DN + (gcol - DN)] = v;
      }
    }
  }
}

// ---------------- edge GEMM: ef_raw = [relu(h_s+h_d) | eattr | ef] @ lin2 + b ----------------
__global__ void __launch_bounds__(256) k_lin2(
    const int* __restrict__ ei, const float* __restrict__ eattr,
    const float* __restrict__ efeat, const u16* __restrict__ hbf,
    const u16* __restrict__ l2wT, const float* __restrict__ lin2b,
    float* __restrict__ efraw)
{
  __shared__ __align__(16) u16 As[64 * KP];
  __shared__ __align__(16) u16 Bs[64 * KP];
  int tid = threadIdx.x;
  int e0 = blockIdx.x * 64;
  {  // stage B (pre-transposed, pre-padded bf16 weights)
    const float4* bs = (const float4*)l2wT;
    float4* bd = (float4*)Bs;
    for (int i = tid; i < 64 * KP * 2 / 16; i += 256) bd[i] = bs[i];
  }
  {  // stage A: 4 threads per edge build the 232-wide bf16 feature row
    int el = tid >> 2, t = tid & 3;
    int e = e0 + el;
    int sn = ei[e], dn = ei[NE + e];
    const s16x8* hs = (const s16x8*)(hbf + sn * DN + t * 32);
    const s16x8* hd = (const s16x8*)(hbf + dn * DN + t * 32);
    s16x8* dst = (s16x8*)(As + el * KP + t * 32);
#pragma unroll
    for (int j = 0; j < 4; ++j) {
      s16x8 a = hs[j], b = hd[j];
      s16x8 o;
#pragma unroll
      for (int i = 0; i < 8; ++i) {
        float v = bf2f((u16)a[i]) + bf2f((u16)b[i]);
        o[i] = (short)f2bf(fmaxf(v, 0.f));
      }
      dst[j] = o;
    }
    if (t < 2) {           // edge_attr -> k [128,192)
      const float4* ap = (const float4*)(eattr + (long)e * DE + t * 32);
      s16x8* ad = (s16x8*)(As + el * KP + DN + t * 32);
#pragma unroll
      for (int j = 0; j < 4; ++j) {
        float4 v0 = ap[2 * j], v1 = ap[2 * j + 1];
        s16x8 o;
        o[0] = (short)f2bf(v0.x); o[1] = (short)f2bf(v0.y);
        o[2] = (short)f2bf(v0.z); o[3] = (short)f2bf(v0.w);
        o[4] = (short)f2bf(v1.x); o[5] = (short)f2bf(v1.y);
        o[6] = (short)f2bf(v1.z); o[7] = (short)f2bf(v1.w);
        ad[j] = o;
      }
    } else if (t == 2) {   // edge_f -> k [192,208)
      const float4* fp = (const float4*)(efeat + (long)e * DF);
      s16x8* fd = (s16x8*)(As + el * KP + DN + DE);
#pragma unroll
      for (int j = 0; j < 2; ++j) {
        float4 v0 = fp[2 * j], v1 = fp[2 * j + 1];
        s16x8 o;
        o[0] = (short)f2bf(v0.x); o[1] = (short)f2bf(v0.y);
        o[2] = (short)f2bf(v0.z); o[3] = (short)f2bf(v0.w);
        o[4] = (short)f2bf(v1.x); o[5] = (short)f2bf(v1.y);
        o[6] = (short)f2bf(v1.z); o[7] = (short)f2bf(v1.w);
        fd[j] = o;
      }
    } else {               // zero pad k [208,232)
      s16x8 z = {0,0,0,0,0,0,0,0};
      s16x8* zd = (s16x8*)(As + el * KP + 208);
      zd[0] = z; zd[1] = z; zd[2] = z;
    }
  }
  __syncthreads();
  int w = tid >> 6, l = tid & 63, lr = l & 15, lg = l >> 4;
  f32x4 acc[4] = {{0,0,0,0},{0,0,0,0},{0,0,0,0},{0,0,0,0}};
  for (int kt = 0; kt < 7; ++kt) {
    s16x8 av = *(const s16x8*)(As + (w * 16 + lr) * KP + kt * 32 + lg * 8);
#pragma unroll
    for (int nt = 0; nt < 4; ++nt) {
      s16x8 bv = *(const s16x8*)(Bs + (nt * 16 + lr) * KP + kt * 32 + lg * 8);
      acc[nt] = __builtin_amdgcn_mfma_f32_16x16x32_bf16(av, bv, acc[nt], 0, 0, 0);
    }
  }
#pragma unroll
  for (int nt = 0; nt < 4; ++nt) {
    int col = nt * 16 + lr;
    float bb = lin2b[col];
#pragma unroll
    for (int rr = 0; rr < 4; ++rr) {
      int e = e0 + w * 16 + lg * 4 + rr;
      efraw[(long)e * DE + col] = acc[nt][rr] + bb;
    }
  }
}

// ---------------- edge BN stats ----------------
__global__ void k_estat(const float* __restrict__ efraw, float* __restrict__ est) {
  int tid = threadIdx.x;
  int c = tid & 63, sub = tid >> 6;
  float s = 0.f, q = 0.f;
  for (long e = blockIdx.x * 4 + sub; e < NE; e += (long)gridDim.x * 4) {
    float v = efraw[e * DE + c];
    s += v; q += v * v;
  }
  __shared__ float lsS[256], lsQ[256];
  lsS[tid] = s; lsQ[tid] = q;
  __syncthreads();
  if (tid < 64) {
    s = lsS[tid] + lsS[tid + 64] + lsS[tid + 128] + lsS[tid + 192];
    q = lsQ[tid] + lsQ[tid + 64] + lsQ[tid + 128] + lsQ[tid + 192];
    int rep = (blockIdx.x & 7) * 128;
    atomicAdd(&est[rep + c], s);
    atomicAdd(&est[rep + 64 + c], q);
  }
}

__global__ void k_estat_fin(const float* __restrict__ est, const float* __restrict__ g,
                            const float* __restrict__ b, float* __restrict__ eab) {
  int c = threadIdx.x;
  if (c < DE) {
    float s = 0.f, q = 0.f;
    for (int r = 0; r < 8; ++r) { s += est[r * 128 + c]; q += est[r * 128 + 64 + c]; }
    float mu = s / (float)NE;
    float var = q / (float)NE - mu * mu;
    float a = rsqrtf(var + EPS) * g[c];
    eab[c] = a;
    eab[DE + c] = b[c] - mu * a;
  }
}

// ---------------- edge BN+relu, out1 residual, edge weight ----------------
__global__ void k_edge2(const float* __restrict__ eattr, const float* __restrict__ eab,
                        const float* __restrict__ linw, const float* __restrict__ linwb,
                        float* __restrict__ efio, float* __restrict__ wbuf)
{
  long e = blockIdx.x * 4 + (threadIdx.x >> 6);
  int c = threadIdx.x & 63;
  float v = efio[e * DE + c];
  float efn = fmaxf(v * eab[c] + eab[DE + c], 0.f);
  efio[e * DE + c] = efn + eattr[e * DE + c];
  float p = efn * linw[c];
#pragma unroll
  for (int off = 32; off > 0; off >>= 1) p += __shfl_xor(p, off);
  if (c == 0) wbuf[e] = fmaxf(p + linwb[0], 0.f);
}

// ---------------- degree / dinv via CSR ----------------
__global__ void k_deg(const int* __restrict__ rowst, const int* __restrict__ csr,
                      const float* __restrict__ wbuf, float* __restrict__ dinv)
{
  int n = blockIdx.x * 4 + (threadIdx.x >> 6);
  int lane = threadIdx.x & 63;
  int a = rowst[n], b = rowst[n + 1];
  float s = 0.f;
  for (int i = a + lane; i < b; i += 64) s += wbuf[csr[i]];
#pragma unroll
  for (int off = 32; off > 0; off >>= 1) s += __shfl_xor(s, off);
  if (lane == 0) dinv[n] = rsqrtf(s + 1.0f);
}

// ---------------- GCN aggregation (node-parallel gather) ----------------
__global__ void __launch_bounds__(128) k_agg(
    const int* __restrict__ ei, const int* __restrict__ rowst, const int* __restrict__ csr,
    const float* __restrict__ wbuf, const float* __restrict__ dinv,
    const float* __restrict__ xw, const float* __restrict__ gcnb,
    float* __restrict__ x1)
{
  int n = blockIdx.x, c = threadIdx.x;
  int a = rowst[n], b = rowst[n + 1];
  float acc = 0.f;
  for (int i = a; i < b; ++i) {
    int eid = csr[i];
    int s = ei[eid];
    acc += wbuf[eid] * dinv[s] * xw[s * DN + c];
  }
  float di = dinv[n];
  x1[n * DN + c] = acc * di + di * di * xw[n * DN + c] + gcnb[c];
}

// ---------------- node BN stats ----------------
__global__ void k_nstat(const float* __restrict__ x1, float* __restrict__ nst) {
  int tid = threadIdx.x;
  int c = tid & 127, sub = tid >> 7;
  float s = 0.f, q = 0.f;
  for (int n = blockIdx.x * 2 + sub; n < NN; n += gridDim.x * 2) {
    float v = x1[n * DN + c];
    s += v; q += v * v;
  }
  __shared__ float lsS[256], lsQ[256];
  lsS[tid] = s; lsQ[tid] = q;
  __syncthreads();
  if (tid < 128) {
    s = lsS[tid] + lsS[tid + 128];
    q = lsQ[tid] + lsQ[tid + 128];
    int rep = (blockIdx.x & 7) * 256;
    atomicAdd(&nst[rep + c], s);
    atomicAdd(&nst[rep + 128 + c], q);
  }
}

__global__ void k_nstat_fin(const float* __restrict__ nst, const float* __restrict__ g,
                            const float* __restrict__ b, float* __restrict__ nab) {
  int c = threadIdx.x;
  if (c < DN) {
    float s = 0.f, q = 0.f;
    for (int r = 0; r < 8; ++r) { s += nst[r * 256 + c]; q += nst[r * 256 + 128 + c]; }
    float mu = s / (float)NN;
    float var = q / (float)NN - mu * mu;
    float a = rsqrtf(var + EPS) * g[c];
    nab[c] = a;
    nab[DN + c] = b[c] - mu * a;
  }
}

// ---------------- out0 = relu(bn(x1)) + x ----------------
__global__ void k_out0(const float* __restrict__ x1, const float* __restrict__ x,
                       const float* __restrict__ nab, float* __restrict__ out0)
{
  int i = blockIdx.x * 256 + threadIdx.x;  // float4 index, total NN*DN/4
  int c0 = (i * 4) & 127;
  float4 v = ((const float4*)x1)[i];
  float4 xv = ((const float4*)x)[i];
  float4 av = *(const float4*)(nab + c0);
  float4 bv = *(const float4*)(nab + DN + c0);
  float4 o;
  o.x = fmaxf(v.x * av.x + bv.x, 0.f) + xv.x;
  o.y = fmaxf(v.y * av.y + bv.y, 0.f) + xv.y;
  o.z = fmaxf(v.z * av.z + bv.z, 0.f) + xv.z;
  o.w = fmaxf(v.w * av.w + bv.w, 0.f) + xv.w;
  ((float4*)out0)[i] = o;
}

extern "C" void kernel_launch(void* const* d_in, const int* in_sizes, int n_in,
                              void* d_out, int out_size, void* d_ws, size_t ws_size,
                              hipStream_t stream)
{
  const float* x     = (const float*)d_in[0];
  const int*   ei    = (const int*)d_in[1];
  const float* efeat = (const float*)d_in[2];
  const float* eattr = (const float*)d_in[3];
  const float* lin1w = (const float*)d_in[4];
  const float* lin1b = (const float*)d_in[5];
  const float* lin2w = (const float*)d_in[6];
  const float* lin2b = (const float*)d_in[7];
  const float* linw  = (const float*)d_in[8];
  const float* linwb = (const float*)d_in[9];
  const float* gcnw  = (const float*)d_in[10];
  const float* gcnb  = (const float*)d_in[11];
  const float* beg   = (const float*)d_in[12];
  const float* beb   = (const float*)d_in[13];
  const float* bng   = (const float*)d_in[14];
  const float* bnb   = (const float*)d_in[15];

  char* wsp = (char*)d_ws;
  size_t off = 0;
  auto alloc = [&](size_t b) { char* p = wsp + off; off += (b + 255) & ~(size_t)255; return p; };
  u16*   xbf    = (u16*)  alloc((size_t)NN * DN * 2);
  u16*   hbf    = (u16*)  alloc((size_t)NN * DN * 2);
  float* xw     = (float*)alloc((size_t)NN * DN * 4);
  float* x1     = (float*)alloc((size_t)NN * DN * 4);
  float* wbuf   = (float*)alloc((size_t)NE * 4);
  int*   csr    = (int*)  alloc((size_t)NE * 4);
  int*   rowst  = (int*)  alloc((size_t)(NN + 1) * 4);
  int*   cur    = (int*)  alloc((size_t)NN * 4);
  float* dinv   = (float*)alloc((size_t)NN * 4);
  int*   blks   = (int*)  alloc(64 * 4);
  u16*   WcatT  = (u16*)  alloc(256 * 128 * 2);
  u16*   l2wT   = (u16*)  alloc(64 * KP * 2);
  float* est    = (float*)alloc(8 * 128 * 4);
  float* eab    = (float*)alloc(128 * 4);
  float* nst    = (float*)alloc(8 * 256 * 4);
  float* nab    = (float*)alloc(256 * 4);

  float* out0  = (float*)d_out;
  float* efraw = (float*)d_out + (size_t)NN * DN;   // out1 region doubles as ef staging

  hipMemsetAsync(cur, 0, (size_t)NN * 4, stream);
  hipMemsetAsync(est, 0, 8 * 128 * 4, stream);
  hipMemsetAsync(nst, 0, 8 * 256 * 4, stream);

  kpre_x<<<1024, 256, 0, stream>>>(x, xbf);
  kpre_w<<<1, 256, 0, stream>>>(lin1w, gcnw, lin2w, WcatT, l2wT);
  khist<<<1024, 256, 0, stream>>>(ei, cur);
  kscan1<<<SCAN_BLOCKS, 256, 0, stream>>>(cur, rowst, blks);
  kscan2<<<1, 64, 0, stream>>>(blks);
  kscan3<<<SCAN_BLOCKS, 256, 0, stream>>>(blks, rowst, cur);
  kscat<<<1024, 256, 0, stream>>>(ei, cur, csr);
  k_nodegemm<<<782 * 4, 256, 0, stream>>>(xbf, WcatT, lin1b, hbf, xw);
  k_lin2<<<NE / 64, 256, 0, stream>>>(ei, eattr, efeat, hbf, l2wT, lin2b, efraw);
  k_estat<<<1024, 256, 0, stream>>>(efraw, est);
  k_estat_fin<<<1, 64, 0, stream>>>(est, beg, beb, eab);
  k_edge2<<<NE / 4, 256, 0, stream>>>(eattr, eab, linw, linwb, efraw, wbuf);
  k_deg<<<NN / 4, 256, 0, stream>>>(rowst, csr, wbuf, dinv);
  k_agg<<<NN, 128, 0, stream>>>(ei, rowst, csr, wbuf, dinv, xw, gcnb, x1);
  k_nstat<<<1024, 256, 0, stream>>>(x1, nst);
  k_nstat_fin<<<1, 128, 0, stream>>>(nst, bng, bnb, nab);
  k_out0<<<NN * DN / 1024, 256, 0, stream>>>(x1, x, nab, out0);
}

// Round 2
// 1023.747 us; speedup vs baseline: 1.1607x; 1.1607x over previous
//
#include <hip/hip_runtime.h>

// Res_EGblk v2: CSR build -> node GEMM (bf16 MFMA) -> edge GEMM lin2 (B frags
// from L1-resident fragment-major table, edge-BN stats fused in epilogue)
// -> edge BN+relu+residual+weight (+deg atomics) -> dinv -> coef -> CSR agg
// -> node BN stats -> BN+relu+residual. efraw staged f32 in out1 region.

#define NN 50000
#define NE 800000
#define DN 128
#define DE 64
#define DF 16
#define KP 232      // LDS A-row stride in shorts (208 data+pad -> stride 232: conflict-free)
#define NKT 7       // K chunks of 32 (224 >= 208)
#define KP1 136
#define EPS 1e-5f
#define SCAN_BLOCKS 49
#define EREP 16

typedef float f32x4 __attribute__((ext_vector_type(4)));
typedef short s16x8 __attribute__((ext_vector_type(8)));
typedef unsigned short u16;

__device__ __forceinline__ float bf2f(u16 u) {
  union { unsigned int i; float f; } v; v.i = ((unsigned int)u) << 16; return v.f;
}
__device__ __forceinline__ u16 f2bf(float f) {
  union { float ff; unsigned int i; } v; v.ff = f;
  unsigned int x = v.i;
  return (u16)((x + 0x7fffu + ((x >> 16) & 1u)) >> 16);   // RNE
}

// ---------------- weight prep ----------------
__global__ void kpre_w(const float* __restrict__ lin1w, const float* __restrict__ gcnw,
                       const float* __restrict__ lin2w,
                       u16* __restrict__ WcatT, u16* __restrict__ l2wF) {
  int t = threadIdx.x;  // 256
  // WcatT[256][128]: transposed [W1 | Wg]
  for (int k = 0; k < DN; ++k) {
    float v = (t < DN) ? lin1w[k * DN + t] : gcnw[k * DN + (t - DN)];
    WcatT[t * DN + k] = f2bf(v);
  }
  // l2wF: fragment-major lin2_w^T. fragment f = kt*256 + nt*64 + l (l = lg*16+lr)
  // holds 8 shorts: B[col = nt*16+lr][k = kt*32 + lg*8 + j], zero for k >= 208.
  for (int f = t; f < NKT * 256; f += 256) {
    int kt = f >> 8, s = f & 255;
    int nt = s >> 6, l = s & 63;
    int lg = l >> 4, lr = l & 15;
    int col = nt * 16 + lr;
    s16x8 o;
#pragma unroll
    for (int j = 0; j < 8; ++j) {
      int k = kt * 32 + lg * 8 + j;
      o[j] = (short)((k < (DN + DE + DF)) ? f2bf(lin2w[k * DE + col]) : (u16)0);
    }
    ((s16x8*)l2wF)[f] = o;
  }
}

// ---------------- CSR build ----------------
__global__ void khist(const int* __restrict__ ei, int* __restrict__ cnt) {
  for (int i = blockIdx.x * blockDim.x + threadIdx.x; i < NE; i += gridDim.x * blockDim.x)
    atomicAdd(&cnt[ei[NE + i]], 1);
}

__global__ void kscan1(const int* __restrict__ cnt, int* __restrict__ rowst, int* __restrict__ blks) {
  __shared__ int ls[256];
  int b = blockIdx.x, t = threadIdx.x;
  int base = b * 1024 + t * 4;
  int c0 = base     < NN ? cnt[base]     : 0;
  int c1 = base + 1 < NN ? cnt[base + 1] : 0;
  int c2 = base + 2 < NN ? cnt[base + 2] : 0;
  int c3 = base + 3 < NN ? cnt[base + 3] : 0;
  int s = c0 + c1 + c2 + c3;
  ls[t] = s; __syncthreads();
  for (int off = 1; off < 256; off <<= 1) {
    int v = (t >= off) ? ls[t - off] : 0;
    __syncthreads();
    ls[t] += v;
    __syncthreads();
  }
  int excl = ls[t] - s;
  if (t == 255) blks[b] = ls[255];
  if (base     < NN) rowst[base]     = excl;
  if (base + 1 < NN) rowst[base + 1] = excl + c0;
  if (base + 2 < NN) rowst[base + 2] = excl + c0 + c1;
  if (base + 3 < NN) rowst[base + 3] = excl + c0 + c1 + c2;
}

__global__ void kscan2(int* __restrict__ blks) {
  if (threadIdx.x == 0) {
    int run = 0;
    for (int i = 0; i < SCAN_BLOCKS; ++i) { int v = blks[i]; blks[i] = run; run += v; }
  }
}

__global__ void kscan3(const int* __restrict__ blks, int* __restrict__ rowst, int* __restrict__ cur) {
  int b = blockIdx.x, t = threadIdx.x;
  int add = blks[b];
  int base = b * 1024 + t * 4;
#pragma unroll
  for (int j = 0; j < 4; ++j) {
    int i = base + j;
    if (i < NN) { int v = rowst[i] + add; rowst[i] = v; cur[i] = v; }
  }
  if (b == 0 && t == 0) rowst[NN] = NE;
}

__global__ void kscat(const int* __restrict__ ei, int* __restrict__ cur, int* __restrict__ csr) {
  for (int i = blockIdx.x * blockDim.x + threadIdx.x; i < NE; i += gridDim.x * blockDim.x) {
    int n = ei[NE + i];
    int p = atomicAdd(&cur[n], 1);
    csr[p] = i;
  }
}

// ---------------- node GEMM: h = x@W1+b1 (bf16), xw = x@Wg (f32) ----------------
__global__ void __launch_bounds__(256) k_nodegemm(
    const float* __restrict__ x, const u16* __restrict__ WcatT,
    const float* __restrict__ lin1b,
    u16* __restrict__ hbf, float* __restrict__ xw)
{
  __shared__ __align__(16) u16 As[64 * KP1];
  __shared__ __align__(16) u16 Bs[64 * KP1];
  int tid = threadIdx.x;
  int tile = blockIdx.x >> 2, ct = blockIdx.x & 3;
  int n0 = tile * 64, c0 = ct * 64;
  int r = tid >> 2, q = tid & 3;
  {
    int n = n0 + r;
    s16x8* dst = (s16x8*)(As + r * KP1 + q * 32);
    if (n < NN) {
      const float4* src = (const float4*)(x + (long)n * DN + q * 32);
#pragma unroll
      for (int j = 0; j < 4; ++j) {
        float4 v0 = src[2 * j], v1 = src[2 * j + 1];
        s16x8 o;
        o[0] = (short)f2bf(v0.x); o[1] = (short)f2bf(v0.y);
        o[2] = (short)f2bf(v0.z); o[3] = (short)f2bf(v0.w);
        o[4] = (short)f2bf(v1.x); o[5] = (short)f2bf(v1.y);
        o[6] = (short)f2bf(v1.z); o[7] = (short)f2bf(v1.w);
        dst[j] = o;
      }
    } else {
      s16x8 z = {0,0,0,0,0,0,0,0};
      dst[0] = z; dst[1] = z; dst[2] = z; dst[3] = z;
    }
    const s16x8* bsrc = (const s16x8*)(WcatT + (c0 + r) * DN + q * 32);
    s16x8* bdst = (s16x8*)(Bs + r * KP1 + q * 32);
    bdst[0] = bsrc[0]; bdst[1] = bsrc[1]; bdst[2] = bsrc[2]; bdst[3] = bsrc[3];
  }
  __syncthreads();
  int w = tid >> 6, l = tid & 63, lr = l & 15, lg = l >> 4;
  f32x4 acc[4] = {{0,0,0,0},{0,0,0,0},{0,0,0,0},{0,0,0,0}};
  for (int kt = 0; kt < 4; ++kt) {
    s16x8 av = *(const s16x8*)(As + (w * 16 + lr) * KP1 + kt * 32 + lg * 8);
#pragma unroll
    for (int nt = 0; nt < 4; ++nt) {
      s16x8 bv = *(const s16x8*)(Bs + (nt * 16 + lr) * KP1 + kt * 32 + lg * 8);
      acc[nt] = __builtin_amdgcn_mfma_f32_16x16x32_bf16(av, bv, acc[nt], 0, 0, 0);
    }
  }
#pragma unroll
  for (int nt = 0; nt < 4; ++nt) {
    int gcol = c0 + nt * 16 + lr;
#pragma unroll
    for (int rr = 0; rr < 4; ++rr) {
      int n = n0 + w * 16 + lg * 4 + rr;
      if (n < NN) {
        float v = acc[nt][rr];
        if (gcol < DN) hbf[n * DN + gcol] = f2bf(v + lin1b[gcol]);
        else           xw[n * DN + (gcol - DN)] = v;
      }
    }
  }
}

// ---------------- edge GEMM + fused BN stats ----------------
__global__ void __launch_bounds__(256) k_lin2(
    const int* __restrict__ ei, const float* __restrict__ eattr,
    const float* __restrict__ efeat, const u16* __restrict__ hbf,
    const u16* __restrict__ l2wF, const float* __restrict__ lin2b,
    float* __restrict__ efraw, float* __restrict__ est)
{
  __shared__ __align__(16) u16 As[64 * KP];
  __shared__ float sS[4][4][16];
  __shared__ float sQ[4][4][16];
  int tid = threadIdx.x;
  int e0 = blockIdx.x * 64;
  {  // stage A: 4 threads per edge build the 224-wide bf16 feature row (stride 232)
    int el = tid >> 2, t = tid & 3;
    int e = e0 + el;
    int sn = ei[e], dn = ei[NE + e];
    const s16x8* hs = (const s16x8*)(hbf + sn * DN + t * 32);
    const s16x8* hd = (const s16x8*)(hbf + dn * DN + t * 32);
    s16x8* dst = (s16x8*)(As + el * KP + t * 32);
#pragma unroll
    for (int j = 0; j < 4; ++j) {
      s16x8 a = hs[j], b = hd[j];
      s16x8 o;
#pragma unroll
      for (int i = 0; i < 8; ++i) {
        float v = bf2f((u16)a[i]) + bf2f((u16)b[i]);
        o[i] = (short)f2bf(fmaxf(v, 0.f));
      }
      dst[j] = o;
    }
    if (t < 2) {           // edge_attr -> shorts [128,192)
      const float4* ap = (const float4*)(eattr + (long)e * DE + t * 32);
      s16x8* ad = (s16x8*)(As + el * KP + DN + t * 32);
#pragma unroll
      for (int j = 0; j < 4; ++j) {
        float4 v0 = ap[2 * j], v1 = ap[2 * j + 1];
        s16x8 o;
        o[0] = (short)f2bf(v0.x); o[1] = (short)f2bf(v0.y);
        o[2] = (short)f2bf(v0.z); o[3] = (short)f2bf(v0.w);
        o[4] = (short)f2bf(v1.x); o[5] = (short)f2bf(v1.y);
        o[6] = (short)f2bf(v1.z); o[7] = (short)f2bf(v1.w);
        ad[j] = o;
      }
    } else if (t == 2) {   // edge_f -> shorts [192,208)
      const float4* fp = (const float4*)(efeat + (long)e * DF);
      s16x8* fd = (s16x8*)(As + el * KP + DN + DE);
#pragma unroll
      for (int j = 0; j < 2; ++j) {
        float4 v0 = fp[2 * j], v1 = fp[2 * j + 1];
        s16x8 o;
        o[0] = (short)f2bf(v0.x); o[1] = (short)f2bf(v0.y);
        o[2] = (short)f2bf(v0.z); o[3] = (short)f2bf(v0.w);
        o[4] = (short)f2bf(v1.x); o[5] = (short)f2bf(v1.y);
        o[6] = (short)f2bf(v1.z); o[7] = (short)f2bf(v1.w);
        fd[j] = o;
      }
    } else {               // zero pad shorts [208,232)
      s16x8 z = {0,0,0,0,0,0,0,0};
      s16x8* zd = (s16x8*)(As + el * KP + 208);
      zd[0] = z; zd[1] = z; zd[2] = z;
    }
  }
  __syncthreads();
  int w = tid >> 6, l = tid & 63, lr = l & 15, lg = l >> 4;
  f32x4 acc[4] = {{0,0,0,0},{0,0,0,0},{0,0,0,0},{0,0,0,0}};
#pragma unroll
  for (int kt = 0; kt < NKT; ++kt) {
    s16x8 av = *(const s16x8*)(As + (w * 16 + lr) * KP + kt * 32 + lg * 8);
#pragma unroll
    for (int nt = 0; nt < 4; ++nt) {
      // B fragment from global: 64 lanes read 1KB contiguous, L1-resident 28KB table
      s16x8 bv = ((const s16x8*)l2wF)[(kt * 4 + nt) * 64 + l];
      acc[nt] = __builtin_amdgcn_mfma_f32_16x16x32_bf16(av, bv, acc[nt], 0, 0, 0);
    }
  }
#pragma unroll
  for (int nt = 0; nt < 4; ++nt) {
    int col = nt * 16 + lr;
    float bb = lin2b[col];
    float sv = 0.f, qv = 0.f;
#pragma unroll
    for (int rr = 0; rr < 4; ++rr) {
      int e = e0 + w * 16 + lg * 4 + rr;
      float v = acc[nt][rr] + bb;
      efraw[(long)e * DE + col] = v;
      sv += v; qv += v * v;
    }
    sv += __shfl_xor(sv, 16); sv += __shfl_xor(sv, 32);
    qv += __shfl_xor(qv, 16); qv += __shfl_xor(qv, 32);
    if (lg == 0) { sS[w][nt][lr] = sv; sQ[w][nt][lr] = qv; }
  }
  __syncthreads();
  if (tid < DE) {
    int nt = tid >> 4, lr2 = tid & 15;
    float s = sS[0][nt][lr2] + sS[1][nt][lr2] + sS[2][nt][lr2] + sS[3][nt][lr2];
    float q = sQ[0][nt][lr2] + sQ[1][nt][lr2] + sQ[2][nt][lr2] + sQ[3][nt][lr2];
    int rep = (blockIdx.x & (EREP - 1)) * 128;
    atomicAdd(&est[rep + tid], s);
    atomicAdd(&est[rep + 64 + tid], q);
  }
}

__global__ void k_estat_fin(const float* __restrict__ est, const float* __restrict__ g,
                            const float* __restrict__ b, float* __restrict__ eab) {
  int c = threadIdx.x;
  if (c < DE) {
    float s = 0.f, q = 0.f;
    for (int r = 0; r < EREP; ++r) { s += est[r * 128 + c]; q += est[r * 128 + 64 + c]; }
    float mu = s / (float)NE;
    float var = q / (float)NE - mu * mu;
    float a = rsqrtf(var + EPS) * g[c];
    eab[c] = a;
    eab[DE + c] = b[c] - mu * a;
  }
}

// ---------------- edge BN+relu, out1 residual, edge weight, deg atomics ----------------
__global__ void k_edge2(const int* __restrict__ ei,
                        const float* __restrict__ eattr, const float* __restrict__ eab,
                        const float* __restrict__ linw, const float* __restrict__ linwb,
                        float* __restrict__ efio, float* __restrict__ wbuf,
                        float* __restrict__ deg)
{
  long e = blockIdx.x * 4 + (threadIdx.x >> 6);
  int c = threadIdx.x & 63;
  float v = efio[e * DE + c];
  float efn = fmaxf(v * eab[c] + eab[DE + c], 0.f);
  efio[e * DE + c] = efn + eattr[e * DE + c];
  float p = efn * linw[c];
#pragma unroll
  for (int off = 32; off > 0; off >>= 1) p += __shfl_xor(p, off);
  if (c == 0) {
    float wv = fmaxf(p + linwb[0], 0.f);
    wbuf[e] = wv;
    atomicAdd(&deg[ei[NE + e]], wv);
  }
}

__global__ void k_dinv(const float* __restrict__ deg, float* __restrict__ dinv) {
  int i = blockIdx.x * 256 + threadIdx.x;
  if (i < NN) dinv[i] = rsqrtf(deg[i] + 1.0f);
}

// ---------------- per-CSR-slot src/coef ----------------
__global__ void k_coef(const int* __restrict__ csr, const int* __restrict__ ei,
                       const float* __restrict__ wbuf, const float* __restrict__ dinv,
                       int* __restrict__ csrsrc, float* __restrict__ csrcoef)
{
  int i = blockIdx.x * 256 + threadIdx.x;
  if (i < NE) {
    int eid = csr[i];
    int s = ei[eid];
    csrsrc[i] = s;
    csrcoef[i] = wbuf[eid] * dinv[s];
  }
}

// ---------------- GCN aggregation (node-parallel gather) ----------------
__global__ void __launch_bounds__(128) k_agg(
    const int* __restrict__ rowst, const int* __restrict__ csrsrc,
    const float* __restrict__ csrcoef, const float* __restrict__ dinv,
    const float* __restrict__ xw, const float* __restrict__ gcnb,
    float* __restrict__ x1)
{
  int n = blockIdx.x, c = threadIdx.x;
  int a = rowst[n], b = rowst[n + 1];
  float acc = 0.f;
  for (int i = a; i < b; ++i) {
    acc += csrcoef[i] * xw[(long)csrsrc[i] * DN + c];
  }
  float di = dinv[n];
  x1[n * DN + c] = acc * di + di * di * xw[n * DN + c] + gcnb[c];
}

// ---------------- node BN stats ----------------
__global__ void k_nstat(const float* __restrict__ x1, float* __restrict__ nst) {
  int tid = threadIdx.x;
  int c = tid & 127, sub = tid >> 7;
  float s = 0.f, q = 0.f;
  for (int n = blockIdx.x * 2 + sub; n < NN; n += gridDim.x * 2) {
    float v = x1[n * DN + c];
    s += v; q += v * v;
  }
  __shared__ float lsS[256], lsQ[256];
  lsS[tid] = s; lsQ[tid] = q;
  __syncthreads();
  if (tid < 128) {
    s = lsS[tid] + lsS[tid + 128];
    q = lsQ[tid] + lsQ[tid + 128];
    int rep = (blockIdx.x & 7) * 256;
    atomicAdd(&nst[rep + c], s);
    atomicAdd(&nst[rep + 128 + c], q);
  }
}

__global__ void k_nstat_fin(const float* __restrict__ nst, const float* __restrict__ g,
                            const float* __restrict__ b, float* __restrict__ nab) {
  int c = threadIdx.x;
  if (c < DN) {
    float s = 0.f, q = 0.f;
    for (int r = 0; r < 8; ++r) { s += nst[r * 256 + c]; q += nst[r * 256 + 128 + c]; }
    float mu = s / (float)NN;
    float var = q / (float)NN - mu * mu;
    float a = rsqrtf(var + EPS) * g[c];
    nab[c] = a;
    nab[DN + c] = b[c] - mu * a;
  }
}

// ---------------- out0 = relu(bn(x1)) + x ----------------
__global__ void k_out0(const float* __restrict__ x1, const float* __restrict__ x,
                       const float* __restrict__ nab, float* __restrict__ out0)
{
  int i = blockIdx.x * 256 + threadIdx.x;
  int c0 = (i * 4) & 127;
  float4 v = ((const float4*)x1)[i];
  float4 xv = ((const float4*)x)[i];
  float4 av = *(const float4*)(nab + c0);
  float4 bv = *(const float4*)(nab + DN + c0);
  float4 o;
  o.x = fmaxf(v.x * av.x + bv.x, 0.f) + xv.x;
  o.y = fmaxf(v.y * av.y + bv.y, 0.f) + xv.y;
  o.z = fmaxf(v.z * av.z + bv.z, 0.f) + xv.z;
  o.w = fmaxf(v.w * av.w + bv.w, 0.f) + xv.w;
  ((float4*)out0)[i] = o;
}

extern "C" void kernel_launch(void* const* d_in, const int* in_sizes, int n_in,
                              void* d_out, int out_size, void* d_ws, size_t ws_size,
                              hipStream_t stream)
{
  const float* x     = (const float*)d_in[0];
  const int*   ei    = (const int*)d_in[1];
  const float* efeat = (const float*)d_in[2];
  const float* eattr = (const float*)d_in[3];
  const float* lin1w = (const float*)d_in[4];
  const float* lin1b = (const float*)d_in[5];
  const float* lin2w = (const float*)d_in[6];
  const float* lin2b = (const float*)d_in[7];
  const float* linw  = (const float*)d_in[8];
  const float* linwb = (const float*)d_in[9];
  const float* gcnw  = (const float*)d_in[10];
  const float* gcnb  = (const float*)d_in[11];
  const float* beg   = (const float*)d_in[12];
  const float* beb   = (const float*)d_in[13];
  const float* bng   = (const float*)d_in[14];
  const float* bnb   = (const float*)d_in[15];

  char* wsp = (char*)d_ws;
  size_t off = 0;
  auto alloc = [&](size_t b) { char* p = wsp + off; off += (b + 255) & ~(size_t)255; return p; };
  u16*   hbf    = (u16*)  alloc((size_t)NN * DN * 2);
  float* xw     = (float*)alloc((size_t)NN * DN * 4);
  float* x1     = (float*)alloc((size_t)NN * DN * 4);
  float* wbuf   = (float*)alloc((size_t)NE * 4);
  int*   csr    = (int*)  alloc((size_t)NE * 4);
  int*   csrsrc = (int*)  alloc((size_t)NE * 4);
  float* csrcoef= (float*)alloc((size_t)NE * 4);
  int*   rowst  = (int*)  alloc((size_t)(NN + 1) * 4);
  int*   cur    = (int*)  alloc((size_t)NN * 4);
  float* dinv   = (float*)alloc((size_t)NN * 4);
  float* deg    = (float*)alloc((size_t)NN * 4);
  int*   blks   = (int*)  alloc(64 * 4);
  u16*   WcatT  = (u16*)  alloc(256 * 128 * 2);
  u16*   l2wF   = (u16*)  alloc((size_t)NKT * 256 * 8 * 2);
  float* est    = (float*)alloc(EREP * 128 * 4);
  float* eab    = (float*)alloc(128 * 4);
  float* nst    = (float*)alloc(8 * 256 * 4);
  float* nab    = (float*)alloc(256 * 4);

  float* out0  = (float*)d_out;
  float* efraw = (float*)d_out + (size_t)NN * DN;   // out1 region doubles as ef staging

  hipMemsetAsync(cur, 0, (size_t)NN * 4, stream);
  hipMemsetAsync(deg, 0, (size_t)NN * 4, stream);
  hipMemsetAsync(est, 0, EREP * 128 * 4, stream);
  hipMemsetAsync(nst, 0, 8 * 256 * 4, stream);

  kpre_w<<<1, 256, 0, stream>>>(lin1w, gcnw, lin2w, WcatT, l2wF);
  khist<<<1024, 256, 0, stream>>>(ei, cur);
  kscan1<<<SCAN_BLOCKS, 256, 0, stream>>>(cur, rowst, blks);
  kscan2<<<1, 64, 0, stream>>>(blks);
  kscan3<<<SCAN_BLOCKS, 256, 0, stream>>>(blks, rowst, cur);
  kscat<<<1024, 256, 0, stream>>>(ei, cur, csr);
  k_nodegemm<<<782 * 4, 256, 0, stream>>>(x, WcatT, lin1b, hbf, xw);
  k_lin2<<<NE / 64, 256, 0, stream>>>(ei, eattr, efeat, hbf, l2wF, lin2b, efraw, est);
  k_estat_fin<<<1, 64, 0, stream>>>(est, beg, beb, eab);
  k_edge2<<<NE / 4, 256, 0, stream>>>(ei, eattr, eab, linw, linwb, efraw, wbuf, deg);
  k_dinv<<<(NN + 255) / 256, 256, 0, stream>>>(deg, dinv);
  k_coef<<<(NE + 255) / 256, 256, 0, stream>>>(csr, ei, wbuf, dinv, csrsrc, csrcoef);
  k_agg<<<NN, 128, 0, stream>>>(rowst, csrsrc, csrcoef, dinv, xw, gcnb, x1);
  k_nstat<<<1024, 256, 0, stream>>>(x1, nst);
  k_nstat_fin<<<1, 128, 0, stream>>>(nst, bng, bnb, nab);
  k_out0<<<NN * DN / 1024, 256, 0, stream>>>(x1, x, nab, out0);
}